// Round 2
// baseline (74.428 us; speedup 1.0000x reference)
//
#include <hip/hip_runtime.h>

#define SDIM 7
#define NPIX 49            // S*S
#define CCH 512
#define FLAT (CCH * NPIX)        // 25088 floats per batch per tensor
#define NG4  (FLAT / 4)          // 6272 float4 per batch per tensor
#define NGRP (CCH / 4)           // 128 4-channel groups
#define THRESH 0.7f
#define EPSN 1e-6f

// One block per batch element b.
// Phase 1 (vectorized): 245 threads = 49 q-slots x 5 group-lanes.
//   Within a 4-channel group (196 floats = 49 float4), float4 #q always
//   covers j = (4q+e) % 49 for e=0..3 (196 % 49 == 0), so each thread
//   accumulates into a STATIC j-quadruple in registers.
//   Per iteration the block reads a contiguous 245-float4 span (coalesced,
//   16B/lane). Partials merged via LDS atomics once at the end.
// Phase 2: cos[j], warp grids.
// Phase 3: 49x49 pair loop -> masked sums; block reduce; atomic accumulate.
__global__ __launch_bounds__(256) void pixpro_main(
    const float4* __restrict__ base4, const float4* __restrict__ moment4,
    const float* __restrict__ pb, const float* __restrict__ pm,
    const int* __restrict__ fb, const int* __restrict__ fm,
    float* __restrict__ accum)  // accum[0]=sum contrib, accum[1]=inter count
{
    const int b   = blockIdx.x;
    const int tid = threadIdx.x;

    __shared__ float lds_sqb[NPIX];
    __shared__ float lds_sqm[NPIX];
    __shared__ float lds_dot[NPIX];
    __shared__ float cosj[NPIX];
    __shared__ float gbx[NPIX], gby[NPIX], gmx[NPIX], gmy[NPIX];
    __shared__ float red[4 * 4];

    if (tid < NPIX) {
        lds_sqb[tid] = 0.f;
        lds_sqm[tid] = 0.f;
        lds_dot[tid] = 0.f;
    }

    // ---- box params (broadcast reads, cached) ----
    const float xb = pb[b * 4 + 0], yb = pb[b * 4 + 1];
    const float wb = pb[b * 4 + 2], hb = pb[b * 4 + 3];
    const float xm = pm[b * 4 + 0], ym = pm[b * 4 + 1];
    const float wm = pm[b * 4 + 2], hm = pm[b * 4 + 3];
    const bool flb = (fb[b] != 0);
    const bool flm = (fm[b] != 0);

    // ---- Phase 1 ----
    float accb[4] = {0.f, 0.f, 0.f, 0.f};   // sum x^2 per element slot
    float accm[4] = {0.f, 0.f, 0.f, 0.f};   // sum y^2
    float accd[4] = {0.f, 0.f, 0.f, 0.f};   // sum x*y

    if (tid < 5 * NPIX) {
        const int q  = tid % NPIX;       // float4 slot within 4-ch group
        const int gl = tid / NPIX;       // group lane 0..4
        const float4* bp = base4   + (size_t)b * NG4 + q;
        const float4* mp = moment4 + (size_t)b * NG4 + q;
        #pragma unroll 2
        for (int g = gl; g < NGRP; g += 5) {
            const float4 x = bp[(size_t)g * NPIX];
            const float4 y = mp[(size_t)g * NPIX];
            accb[0] = fmaf(x.x, x.x, accb[0]);
            accm[0] = fmaf(y.x, y.x, accm[0]);
            accd[0] = fmaf(x.x, y.x, accd[0]);
            accb[1] = fmaf(x.y, x.y, accb[1]);
            accm[1] = fmaf(y.y, y.y, accm[1]);
            accd[1] = fmaf(x.y, y.y, accd[1]);
            accb[2] = fmaf(x.z, x.z, accb[2]);
            accm[2] = fmaf(y.z, y.z, accm[2]);
            accd[2] = fmaf(x.z, y.z, accd[2]);
            accb[3] = fmaf(x.w, x.w, accb[3]);
            accm[3] = fmaf(y.w, y.w, accm[3]);
            accd[3] = fmaf(x.w, y.w, accd[3]);
        }
    }
    __syncthreads();   // zeroes visible before atomics

    if (tid < 5 * NPIX) {
        const int q = tid % NPIX;
        #pragma unroll
        for (int e = 0; e < 4; ++e) {
            const int j = (4 * q + e) % NPIX;   // static per (q,e)
            atomicAdd(&lds_sqb[j], accb[e]);
            atomicAdd(&lds_sqm[j], accm[e]);
            atomicAdd(&lds_dot[j], accd[e]);
        }
    }
    __syncthreads();

    // ---- Phase 2: cos[j] and warp grids ----
    if (tid < NPIX) {
        float nb = fmaxf(sqrtf(lds_sqb[tid]), EPSN);
        float nm = fmaxf(sqrtf(lds_sqm[tid]), EPSN);
        cosj[tid] = lds_dot[tid] / (nb * nm);

        // grid: n = i*7 + jj ; g[i][jj] = (gx[i], gy[flip ? 6-jj : jj])
        const int i  = tid / SDIM;
        const int jj = tid % SDIM;
        const float ti = (float)i * (1.0f / 6.0f);
        const int jb = flb ? (6 - jj) : jj;
        const int jm = flm ? (6 - jj) : jj;
        gbx[tid] = xb + wb * ti;
        gby[tid] = yb + hb * ((float)jb * (1.0f / 6.0f));
        gmx[tid] = xm + wm * ti;
        gmy[tid] = ym + hm * ((float)jm * (1.0f / 6.0f));
    }
    __syncthreads();

    // ---- Phase 3: 49x49 pairs ----
    // A_b[i][j]: dist(gb[i],gm[j]) < 0.7*diag_b -> s_b += cos[j]
    // A_m (after swapaxes): dist(gb[i],gm[j]) < 0.7*diag_m -> s_m += cos[i]
    const float thrb2 = THRESH * THRESH * (wb * wb + hb * hb);
    const float thrm2 = THRESH * THRESH * (wm * wm + hm * hm);
    float sb = 0.f, sm = 0.f;
    int nnzb = 0, nnzm = 0;
    for (int p = tid; p < NPIX * NPIX; p += 256) {
        const int i = p / NPIX;
        const int j = p - i * NPIX;
        const float dx = gbx[i] - gmx[j];
        const float dy = gby[i] - gmy[j];
        const float d2 = dx * dx + dy * dy;
        if (d2 < thrb2) { ++nnzb; sb += cosj[j]; }
        if (d2 < thrm2) { ++nnzm; sm += cosj[i]; }
    }

    // wave (64-lane) shuffle reduction, then cross-wave via LDS
    for (int off = 32; off; off >>= 1) {
        sb   += __shfl_down(sb, off);
        sm   += __shfl_down(sm, off);
        nnzb += __shfl_down(nnzb, off);
        nnzm += __shfl_down(nnzm, off);
    }
    const int wid = tid >> 6;
    if ((tid & 63) == 0) {
        red[wid * 4 + 0] = sb;
        red[wid * 4 + 1] = sm;
        red[wid * 4 + 2] = (float)nnzb;
        red[wid * 4 + 3] = (float)nnzm;
    }
    __syncthreads();

    if (tid == 0) {
        float SB = 0.f, SM = 0.f, NB = 0.f, NM = 0.f;
        for (int w = 0; w < 4; ++w) {
            SB += red[w * 4 + 0];
            SM += red[w * 4 + 1];
            NB += red[w * 4 + 2];
            NM += red[w * 4 + 3];
        }
        const float lossb = (NB > 0.f) ? SB / NB : 0.f;
        const float lossm = (NM > 0.f) ? SM / NM : 0.f;
        const float cx1 = xb + 0.5f * wb, cx2 = xm + 0.5f * wm;
        const float cy1 = yb + 0.5f * hb, cy2 = ym + 0.5f * hm;
        const bool inter = (fabsf(cx1 - cx2) * 2.f < wb + wm) &&
                           (fabsf(cy1 - cy2) * 2.f < hb + hm);
        if (inter) {
            atomicAdd(&accum[0], -(lossb + lossm));
            atomicAdd(&accum[1], 1.0f);
        }
    }
}

__global__ void pixpro_final(const float* __restrict__ accum,
                             float* __restrict__ out)
{
    out[0] = accum[0] / fmaxf(accum[1], 1.0f);
}

extern "C" void kernel_launch(void* const* d_in, const int* in_sizes, int n_in,
                              void* d_out, int out_size, void* d_ws, size_t ws_size,
                              hipStream_t stream)
{
    const float4* base4   = (const float4*)d_in[0];
    const float4* moment4 = (const float4*)d_in[1];
    const float*  pbase   = (const float*)d_in[2];
    const float*  pmom    = (const float*)d_in[3];
    const int*    fbase   = (const int*)d_in[4];
    const int*    fmom    = (const int*)d_in[5];
    float* out   = (float*)d_out;
    float* accum = (float*)d_ws;  // 2 floats

    const int B = in_sizes[2] / 4;  // p_base is (B,4)

    hipMemsetAsync(accum, 0, 2 * sizeof(float), stream);
    pixpro_main<<<B, 256, 0, stream>>>(base4, moment4, pbase, pmom, fbase, fmom, accum);
    pixpro_final<<<1, 1, 0, stream>>>(accum, out);
}

// Round 3
// 72.875 us; speedup vs baseline: 1.0213x; 1.0213x over previous
//
#include <hip/hip_runtime.h>

#define SDIM 7
#define NPIX 49                  // S*S
#define CCH 512
#define FLAT (CCH * NPIX)        // 25088 floats per batch per tensor
#define NG4  (FLAT / 4)          // 6272 float4 per batch per tensor
#define NGRP (CCH / 4)           // 128 4-channel groups
#define CHUNKS 4
#define GPC (NGRP / CHUNKS)      // 32 groups per chunk
#define KITER (GPC / 4)          // 8 groups per gl-lane
#define THRESH 0.7f
#define EPSN 1e-6f

// ============================= Kernel A ====================================
// grid = B*CHUNKS blocks. Block (b,chunk) reduces 128 channels for all 49
// pixels. 196 active threads = 49 q-slots x 4 gl-lanes; each thread stages
// 8+8 float4 loads into registers (static arrays -> VGPRs, deep MLP), then
// accumulates into a static j-quadruple (196 % 49 == 0). LDS-atomic merge,
// then 147 partial floats written to a PRIVATE ws slot (no global atomics).
__global__ __launch_bounds__(256) void pixpro_reduce(
    const float4* __restrict__ base4, const float4* __restrict__ moment4,
    float* __restrict__ partial)
{
    const int bid   = blockIdx.x;
    const int b     = bid >> 2;
    const int chunk = bid & 3;
    const int tid   = threadIdx.x;

    __shared__ float lds[3 * NPIX];
    if (tid < 3 * NPIX) lds[tid] = 0.f;
    __syncthreads();

    if (tid < 4 * NPIX) {
        const int q  = tid % NPIX;       // float4 slot within a 4-ch group
        const int gl = tid / NPIX;       // 0..3
        const float4* bp = base4   + (size_t)b * NG4
                         + (size_t)(chunk * GPC + gl) * NPIX + q;
        const float4* mp = moment4 + (size_t)b * NG4
                         + (size_t)(chunk * GPC + gl) * NPIX + q;

        float4 xs[KITER], ys[KITER];
        #pragma unroll
        for (int k = 0; k < KITER; ++k) {
            xs[k] = bp[(size_t)(4 * k) * NPIX];   // g = chunk*32 + gl + 4k
            ys[k] = mp[(size_t)(4 * k) * NPIX];
        }

        float accb[4] = {0.f, 0.f, 0.f, 0.f};
        float accm[4] = {0.f, 0.f, 0.f, 0.f};
        float accd[4] = {0.f, 0.f, 0.f, 0.f};
        #pragma unroll
        for (int k = 0; k < KITER; ++k) {
            const float4 x = xs[k];
            const float4 y = ys[k];
            accb[0] = fmaf(x.x, x.x, accb[0]);
            accm[0] = fmaf(y.x, y.x, accm[0]);
            accd[0] = fmaf(x.x, y.x, accd[0]);
            accb[1] = fmaf(x.y, x.y, accb[1]);
            accm[1] = fmaf(y.y, y.y, accm[1]);
            accd[1] = fmaf(x.y, y.y, accd[1]);
            accb[2] = fmaf(x.z, x.z, accb[2]);
            accm[2] = fmaf(y.z, y.z, accm[2]);
            accd[2] = fmaf(x.z, y.z, accd[2]);
            accb[3] = fmaf(x.w, x.w, accb[3]);
            accm[3] = fmaf(y.w, y.w, accm[3]);
            accd[3] = fmaf(x.w, y.w, accd[3]);
        }
        #pragma unroll
        for (int e = 0; e < 4; ++e) {
            const int j = (4 * q + e) % NPIX;   // static per (q,e)
            atomicAdd(&lds[j],            accb[e]);
            atomicAdd(&lds[NPIX + j],     accm[e]);
            atomicAdd(&lds[2 * NPIX + j], accd[e]);
        }
    }
    __syncthreads();

    if (tid < 3 * NPIX)
        partial[(size_t)bid * (3 * NPIX) + tid] = lds[tid];
}

// ============================= Kernel B ====================================
// One 64-thread block (single wave) per batch b: merge 4 chunk partials ->
// cos[j]; warp grids; 49x49 pair loop; write (contrib, interFlag) to slot b.
__global__ __launch_bounds__(64) void pixpro_pairs(
    const float* __restrict__ partial,
    const float* __restrict__ pb, const float* __restrict__ pm,
    const int* __restrict__ fb, const int* __restrict__ fm,
    float* __restrict__ perb)
{
    const int b   = blockIdx.x;
    const int tid = threadIdx.x;

    __shared__ float cosj[NPIX];
    __shared__ float gbx[NPIX], gby[NPIX], gmx[NPIX], gmy[NPIX];

    const float xb = pb[b * 4 + 0], yb = pb[b * 4 + 1];
    const float wb = pb[b * 4 + 2], hb = pb[b * 4 + 3];
    const float xm = pm[b * 4 + 0], ym = pm[b * 4 + 1];
    const float wm = pm[b * 4 + 2], hm = pm[b * 4 + 3];
    const bool flb = (fb[b] != 0);
    const bool flm = (fm[b] != 0);

    if (tid < NPIX) {
        float sqb = 0.f, sqm = 0.f, dt = 0.f;
        #pragma unroll
        for (int c = 0; c < CHUNKS; ++c) {
            const float* p = partial + (size_t)(b * CHUNKS + c) * (3 * NPIX);
            sqb += p[tid];
            sqm += p[NPIX + tid];
            dt  += p[2 * NPIX + tid];
        }
        const float nb = fmaxf(sqrtf(sqb), EPSN);
        const float nm = fmaxf(sqrtf(sqm), EPSN);
        cosj[tid] = dt / (nb * nm);

        // grid: n = i*7 + jj ; g[i][jj] = (gx[i], gy[flip ? 6-jj : jj])
        const int i  = tid / SDIM;
        const int jj = tid % SDIM;
        const float ti = (float)i * (1.0f / 6.0f);
        const int jb = flb ? (6 - jj) : jj;
        const int jm = flm ? (6 - jj) : jj;
        gbx[tid] = xb + wb * ti;
        gby[tid] = yb + hb * ((float)jb * (1.0f / 6.0f));
        gmx[tid] = xm + wm * ti;
        gmy[tid] = ym + hm * ((float)jm * (1.0f / 6.0f));
    }
    __syncthreads();

    // A_b[i][j]: dist(gb[i],gm[j]) < 0.7*diag_b -> s_b += cos[j]
    // A_m (after swapaxes): dist(gb[i],gm[j]) < 0.7*diag_m -> s_m += cos[i]
    const float thrb2 = THRESH * THRESH * (wb * wb + hb * hb);
    const float thrm2 = THRESH * THRESH * (wm * wm + hm * hm);
    float sb = 0.f, sm = 0.f;
    int nnzb = 0, nnzm = 0;
    for (int p = tid; p < NPIX * NPIX; p += 64) {
        const int i = p / NPIX;
        const int j = p - i * NPIX;
        const float dx = gbx[i] - gmx[j];
        const float dy = gby[i] - gmy[j];
        const float d2 = dx * dx + dy * dy;
        if (d2 < thrb2) { ++nnzb; sb += cosj[j]; }
        if (d2 < thrm2) { ++nnzm; sm += cosj[i]; }
    }
    #pragma unroll
    for (int off = 32; off; off >>= 1) {
        sb   += __shfl_down(sb, off);
        sm   += __shfl_down(sm, off);
        nnzb += __shfl_down(nnzb, off);
        nnzm += __shfl_down(nnzm, off);
    }
    if (tid == 0) {
        const float lossb = (nnzb > 0) ? sb / (float)nnzb : 0.f;
        const float lossm = (nnzm > 0) ? sm / (float)nnzm : 0.f;
        const float cx1 = xb + 0.5f * wb, cx2 = xm + 0.5f * wm;
        const float cy1 = yb + 0.5f * hb, cy2 = ym + 0.5f * hm;
        const bool inter = (fabsf(cx1 - cx2) * 2.f < wb + wm) &&
                           (fabsf(cy1 - cy2) * 2.f < hb + hm);
        perb[b * 2 + 0] = inter ? -(lossb + lossm) : 0.f;
        perb[b * 2 + 1] = inter ? 1.f : 0.f;
    }
}

// ============================= Kernel C ====================================
__global__ __launch_bounds__(1024) void pixpro_final(
    const float* __restrict__ perb, float* __restrict__ out, int B)
{
    const int tid = threadIdx.x;
    float c = 0.f, n = 0.f;
    for (int i = tid; i < B; i += 1024) {
        c += perb[2 * i + 0];
        n += perb[2 * i + 1];
    }
    #pragma unroll
    for (int off = 32; off; off >>= 1) {
        c += __shfl_down(c, off);
        n += __shfl_down(n, off);
    }
    __shared__ float red[32];
    const int wid = tid >> 6;
    if ((tid & 63) == 0) { red[wid * 2] = c; red[wid * 2 + 1] = n; }
    __syncthreads();
    if (tid == 0) {
        float C = 0.f, N = 0.f;
        for (int w = 0; w < 16; ++w) { C += red[w * 2]; N += red[w * 2 + 1]; }
        out[0] = C / fmaxf(N, 1.0f);
    }
}

// ===================== Fallback mono kernel (small ws) =====================
__global__ __launch_bounds__(256) void pixpro_mono(
    const float4* __restrict__ base4, const float4* __restrict__ moment4,
    const float* __restrict__ pb, const float* __restrict__ pm,
    const int* __restrict__ fb, const int* __restrict__ fm,
    float* __restrict__ accum)
{
    const int b   = blockIdx.x;
    const int tid = threadIdx.x;
    __shared__ float lds_sqb[NPIX], lds_sqm[NPIX], lds_dot[NPIX];
    __shared__ float cosj[NPIX], gbx[NPIX], gby[NPIX], gmx[NPIX], gmy[NPIX];
    __shared__ float red[16];
    if (tid < NPIX) { lds_sqb[tid]=0.f; lds_sqm[tid]=0.f; lds_dot[tid]=0.f; }
    const float xb = pb[b*4+0], yb = pb[b*4+1], wb = pb[b*4+2], hb = pb[b*4+3];
    const float xm = pm[b*4+0], ym = pm[b*4+1], wm = pm[b*4+2], hm = pm[b*4+3];
    const bool flb = (fb[b] != 0), flm = (fm[b] != 0);
    float accb[4]={0,0,0,0}, accm[4]={0,0,0,0}, accd[4]={0,0,0,0};
    if (tid < 5 * NPIX) {
        const int q = tid % NPIX, gl = tid / NPIX;
        const float4* bp = base4   + (size_t)b * NG4 + q;
        const float4* mp = moment4 + (size_t)b * NG4 + q;
        for (int g = gl; g < NGRP; g += 5) {
            const float4 x = bp[(size_t)g * NPIX];
            const float4 y = mp[(size_t)g * NPIX];
            accb[0]=fmaf(x.x,x.x,accb[0]); accm[0]=fmaf(y.x,y.x,accm[0]); accd[0]=fmaf(x.x,y.x,accd[0]);
            accb[1]=fmaf(x.y,x.y,accb[1]); accm[1]=fmaf(y.y,y.y,accm[1]); accd[1]=fmaf(x.y,y.y,accd[1]);
            accb[2]=fmaf(x.z,x.z,accb[2]); accm[2]=fmaf(y.z,y.z,accm[2]); accd[2]=fmaf(x.z,y.z,accd[2]);
            accb[3]=fmaf(x.w,x.w,accb[3]); accm[3]=fmaf(y.w,y.w,accm[3]); accd[3]=fmaf(x.w,y.w,accd[3]);
        }
    }
    __syncthreads();
    if (tid < 5 * NPIX) {
        const int q = tid % NPIX;
        #pragma unroll
        for (int e = 0; e < 4; ++e) {
            const int j = (4 * q + e) % NPIX;
            atomicAdd(&lds_sqb[j], accb[e]);
            atomicAdd(&lds_sqm[j], accm[e]);
            atomicAdd(&lds_dot[j], accd[e]);
        }
    }
    __syncthreads();
    if (tid < NPIX) {
        float nb = fmaxf(sqrtf(lds_sqb[tid]), EPSN);
        float nm = fmaxf(sqrtf(lds_sqm[tid]), EPSN);
        cosj[tid] = lds_dot[tid] / (nb * nm);
        const int i = tid / SDIM, jj = tid % SDIM;
        const float ti = (float)i * (1.0f/6.0f);
        const int jb = flb ? (6-jj) : jj, jm = flm ? (6-jj) : jj;
        gbx[tid] = xb + wb * ti;
        gby[tid] = yb + hb * ((float)jb * (1.0f/6.0f));
        gmx[tid] = xm + wm * ti;
        gmy[tid] = ym + hm * ((float)jm * (1.0f/6.0f));
    }
    __syncthreads();
    const float thrb2 = THRESH*THRESH*(wb*wb+hb*hb);
    const float thrm2 = THRESH*THRESH*(wm*wm+hm*hm);
    float sb = 0.f, sm = 0.f; int nnzb = 0, nnzm = 0;
    for (int p = tid; p < NPIX*NPIX; p += 256) {
        const int i = p / NPIX, j = p - i*NPIX;
        const float dx = gbx[i]-gmx[j], dy = gby[i]-gmy[j];
        const float d2 = dx*dx + dy*dy;
        if (d2 < thrb2) { ++nnzb; sb += cosj[j]; }
        if (d2 < thrm2) { ++nnzm; sm += cosj[i]; }
    }
    for (int off = 32; off; off >>= 1) {
        sb += __shfl_down(sb,off); sm += __shfl_down(sm,off);
        nnzb += __shfl_down(nnzb,off); nnzm += __shfl_down(nnzm,off);
    }
    const int wid = tid >> 6;
    if ((tid & 63) == 0) {
        red[wid*4+0]=sb; red[wid*4+1]=sm; red[wid*4+2]=(float)nnzb; red[wid*4+3]=(float)nnzm;
    }
    __syncthreads();
    if (tid == 0) {
        float SB=0,SM=0,NB=0,NM=0;
        for (int w=0;w<4;++w){SB+=red[w*4+0];SM+=red[w*4+1];NB+=red[w*4+2];NM+=red[w*4+3];}
        const float lossb = (NB>0.f)?SB/NB:0.f, lossm = (NM>0.f)?SM/NM:0.f;
        const float cx1=xb+0.5f*wb, cx2=xm+0.5f*wm, cy1=yb+0.5f*hb, cy2=ym+0.5f*hm;
        const bool inter = (fabsf(cx1-cx2)*2.f < wb+wm) && (fabsf(cy1-cy2)*2.f < hb+hm);
        if (inter) { atomicAdd(&accum[0], -(lossb+lossm)); atomicAdd(&accum[1], 1.f); }
    }
}

__global__ void pixpro_mono_final(const float* __restrict__ accum,
                                  float* __restrict__ out)
{
    out[0] = accum[0] / fmaxf(accum[1], 1.0f);
}

// ============================= launch ======================================
extern "C" void kernel_launch(void* const* d_in, const int* in_sizes, int n_in,
                              void* d_out, int out_size, void* d_ws, size_t ws_size,
                              hipStream_t stream)
{
    const float4* base4   = (const float4*)d_in[0];
    const float4* moment4 = (const float4*)d_in[1];
    const float*  pbase   = (const float*)d_in[2];
    const float*  pmom    = (const float*)d_in[3];
    const int*    fbase   = (const int*)d_in[4];
    const int*    fmom    = (const int*)d_in[5];
    float* out = (float*)d_out;

    const int B = in_sizes[2] / 4;  // p_base is (B,4)

    const size_t need = (size_t)B * CHUNKS * (3 * NPIX) * sizeof(float)
                      + (size_t)B * 2 * sizeof(float);
    if (ws_size >= need) {
        float* partial = (float*)d_ws;
        float* perb    = partial + (size_t)B * CHUNKS * (3 * NPIX);
        pixpro_reduce<<<B * CHUNKS, 256, 0, stream>>>(base4, moment4, partial);
        pixpro_pairs<<<B, 64, 0, stream>>>(partial, pbase, pmom, fbase, fmom, perb);
        pixpro_final<<<1, 1024, 0, stream>>>(perb, out, B);
    } else {
        float* accum = (float*)d_ws;  // 2 floats
        hipMemsetAsync(accum, 0, 2 * sizeof(float), stream);
        pixpro_mono<<<B, 256, 0, stream>>>(base4, moment4, pbase, pmom, fbase, fmom, accum);
        pixpro_mono_final<<<1, 1, 0, stream>>>(accum, out);
    }
}

// Round 4
// 72.786 us; speedup vs baseline: 1.0226x; 1.0012x over previous
//
#include <hip/hip_runtime.h>

#define SDIM 7
#define NPIX 49                  // S*S
#define CCH 512
#define FLAT (CCH * NPIX)        // 25088 floats per batch per tensor
#define NG4  (FLAT / 4)          // 6272 float4 per batch per tensor
#define NGRP (CCH / 4)           // 128 4-channel groups
#define CHUNKS 4
#define GPC (NGRP / CHUNKS)      // 32 groups per chunk
#define KITER (GPC / 4)          // 8 groups per gl-lane
#define THRESH 0.7f
#define EPSN 1e-6f

// ============================= Kernel A ====================================
// grid = B*CHUNKS blocks. Block (b,chunk) reduces 128 channels for all 49
// pixels. 196 active threads = 49 q-slots x 4 gl-lanes; each thread stages
// 8+8 float4 loads into registers. sched_barrier(0) pins the staging: the
// compiler may NOT sink loads past it into the FMA loop (R3 failure mode:
// VGPR=32, ~2 loads in flight, latency-bound at 1.2 TB/s). With the fence,
// 16 loads/thread stay in flight -> request queues saturate.
__global__ __launch_bounds__(256) void pixpro_reduce(
    const float4* __restrict__ base4, const float4* __restrict__ moment4,
    float* __restrict__ partial)
{
    const int bid   = blockIdx.x;
    const int b     = bid >> 2;
    const int chunk = bid & 3;
    const int tid   = threadIdx.x;

    __shared__ float lds[3 * NPIX];
    if (tid < 3 * NPIX) lds[tid] = 0.f;
    __syncthreads();

    if (tid < 4 * NPIX) {
        const int q  = tid % NPIX;       // float4 slot within a 4-ch group
        const int gl = tid / NPIX;       // 0..3
        const float4* bp = base4   + (size_t)b * NG4
                         + (size_t)(chunk * GPC + gl) * NPIX + q;
        const float4* mp = moment4 + (size_t)b * NG4
                         + (size_t)(chunk * GPC + gl) * NPIX + q;

        float4 xs[KITER], ys[KITER];
        #pragma unroll
        for (int k = 0; k < KITER; ++k) {
            xs[k] = bp[(size_t)(4 * k) * NPIX];   // g = chunk*32 + gl + 4k
            ys[k] = mp[(size_t)(4 * k) * NPIX];
        }

        // Scheduling fence: all 16 loads above must ISSUE before anything
        // below. Keeps 16 global_load_dwordx4 outstanding per thread.
        __builtin_amdgcn_sched_barrier(0);

        float accb[4] = {0.f, 0.f, 0.f, 0.f};
        float accm[4] = {0.f, 0.f, 0.f, 0.f};
        float accd[4] = {0.f, 0.f, 0.f, 0.f};
        #pragma unroll
        for (int k = 0; k < KITER; ++k) {
            const float4 x = xs[k];
            const float4 y = ys[k];
            accb[0] = fmaf(x.x, x.x, accb[0]);
            accm[0] = fmaf(y.x, y.x, accm[0]);
            accd[0] = fmaf(x.x, y.x, accd[0]);
            accb[1] = fmaf(x.y, x.y, accb[1]);
            accm[1] = fmaf(y.y, y.y, accm[1]);
            accd[1] = fmaf(x.y, y.y, accd[1]);
            accb[2] = fmaf(x.z, x.z, accb[2]);
            accm[2] = fmaf(y.z, y.z, accm[2]);
            accd[2] = fmaf(x.z, y.z, accd[2]);
            accb[3] = fmaf(x.w, x.w, accb[3]);
            accm[3] = fmaf(y.w, y.w, accm[3]);
            accd[3] = fmaf(x.w, y.w, accd[3]);
        }
        #pragma unroll
        for (int e = 0; e < 4; ++e) {
            const int j = (4 * q + e) % NPIX;   // static per (q,e)
            atomicAdd(&lds[j],            accb[e]);
            atomicAdd(&lds[NPIX + j],     accm[e]);
            atomicAdd(&lds[2 * NPIX + j], accd[e]);
        }
    }
    __syncthreads();

    if (tid < 3 * NPIX)
        partial[(size_t)bid * (3 * NPIX) + tid] = lds[tid];
}

// ============================= Kernel B ====================================
// One 64-thread block (single wave) per batch b: merge 4 chunk partials ->
// cos[j]; warp grids; 49x49 pair loop; write (contrib, interFlag) to slot b.
__global__ __launch_bounds__(64) void pixpro_pairs(
    const float* __restrict__ partial,
    const float* __restrict__ pb, const float* __restrict__ pm,
    const int* __restrict__ fb, const int* __restrict__ fm,
    float* __restrict__ perb)
{
    const int b   = blockIdx.x;
    const int tid = threadIdx.x;

    __shared__ float cosj[NPIX];
    __shared__ float gbx[NPIX], gby[NPIX], gmx[NPIX], gmy[NPIX];

    const float xb = pb[b * 4 + 0], yb = pb[b * 4 + 1];
    const float wb = pb[b * 4 + 2], hb = pb[b * 4 + 3];
    const float xm = pm[b * 4 + 0], ym = pm[b * 4 + 1];
    const float wm = pm[b * 4 + 2], hm = pm[b * 4 + 3];
    const bool flb = (fb[b] != 0);
    const bool flm = (fm[b] != 0);

    if (tid < NPIX) {
        float sqb = 0.f, sqm = 0.f, dt = 0.f;
        #pragma unroll
        for (int c = 0; c < CHUNKS; ++c) {
            const float* p = partial + (size_t)(b * CHUNKS + c) * (3 * NPIX);
            sqb += p[tid];
            sqm += p[NPIX + tid];
            dt  += p[2 * NPIX + tid];
        }
        const float nb = fmaxf(sqrtf(sqb), EPSN);
        const float nm = fmaxf(sqrtf(sqm), EPSN);
        cosj[tid] = dt / (nb * nm);

        // grid: n = i*7 + jj ; g[i][jj] = (gx[i], gy[flip ? 6-jj : jj])
        const int i  = tid / SDIM;
        const int jj = tid % SDIM;
        const float ti = (float)i * (1.0f / 6.0f);
        const int jb = flb ? (6 - jj) : jj;
        const int jm = flm ? (6 - jj) : jj;
        gbx[tid] = xb + wb * ti;
        gby[tid] = yb + hb * ((float)jb * (1.0f / 6.0f));
        gmx[tid] = xm + wm * ti;
        gmy[tid] = ym + hm * ((float)jm * (1.0f / 6.0f));
    }
    __syncthreads();

    // A_b[i][j]: dist(gb[i],gm[j]) < 0.7*diag_b -> s_b += cos[j]
    // A_m (after swapaxes): dist(gb[i],gm[j]) < 0.7*diag_m -> s_m += cos[i]
    const float thrb2 = THRESH * THRESH * (wb * wb + hb * hb);
    const float thrm2 = THRESH * THRESH * (wm * wm + hm * hm);
    float sb = 0.f, sm = 0.f;
    int nnzb = 0, nnzm = 0;
    for (int p = tid; p < NPIX * NPIX; p += 64) {
        const int i = p / NPIX;
        const int j = p - i * NPIX;
        const float dx = gbx[i] - gmx[j];
        const float dy = gby[i] - gmy[j];
        const float d2 = dx * dx + dy * dy;
        if (d2 < thrb2) { ++nnzb; sb += cosj[j]; }
        if (d2 < thrm2) { ++nnzm; sm += cosj[i]; }
    }
    #pragma unroll
    for (int off = 32; off; off >>= 1) {
        sb   += __shfl_down(sb, off);
        sm   += __shfl_down(sm, off);
        nnzb += __shfl_down(nnzb, off);
        nnzm += __shfl_down(nnzm, off);
    }
    if (tid == 0) {
        const float lossb = (nnzb > 0) ? sb / (float)nnzb : 0.f;
        const float lossm = (nnzm > 0) ? sm / (float)nnzm : 0.f;
        const float cx1 = xb + 0.5f * wb, cx2 = xm + 0.5f * wm;
        const float cy1 = yb + 0.5f * hb, cy2 = ym + 0.5f * hm;
        const bool inter = (fabsf(cx1 - cx2) * 2.f < wb + wm) &&
                           (fabsf(cy1 - cy2) * 2.f < hb + hm);
        perb[b * 2 + 0] = inter ? -(lossb + lossm) : 0.f;
        perb[b * 2 + 1] = inter ? 1.f : 0.f;
    }
}

// ============================= Kernel C ====================================
__global__ __launch_bounds__(1024) void pixpro_final(
    const float* __restrict__ perb, float* __restrict__ out, int B)
{
    const int tid = threadIdx.x;
    float c = 0.f, n = 0.f;
    for (int i = tid; i < B; i += 1024) {
        c += perb[2 * i + 0];
        n += perb[2 * i + 1];
    }
    #pragma unroll
    for (int off = 32; off; off >>= 1) {
        c += __shfl_down(c, off);
        n += __shfl_down(n, off);
    }
    __shared__ float red[32];
    const int wid = tid >> 6;
    if ((tid & 63) == 0) { red[wid * 2] = c; red[wid * 2 + 1] = n; }
    __syncthreads();
    if (tid == 0) {
        float C = 0.f, N = 0.f;
        for (int w = 0; w < 16; ++w) { C += red[w * 2]; N += red[w * 2 + 1]; }
        out[0] = C / fmaxf(N, 1.0f);
    }
}

// ===================== Fallback mono kernel (small ws) =====================
__global__ __launch_bounds__(256) void pixpro_mono(
    const float4* __restrict__ base4, const float4* __restrict__ moment4,
    const float* __restrict__ pb, const float* __restrict__ pm,
    const int* __restrict__ fb, const int* __restrict__ fm,
    float* __restrict__ accum)
{
    const int b   = blockIdx.x;
    const int tid = threadIdx.x;
    __shared__ float lds_sqb[NPIX], lds_sqm[NPIX], lds_dot[NPIX];
    __shared__ float cosj[NPIX], gbx[NPIX], gby[NPIX], gmx[NPIX], gmy[NPIX];
    __shared__ float red[16];
    if (tid < NPIX) { lds_sqb[tid]=0.f; lds_sqm[tid]=0.f; lds_dot[tid]=0.f; }
    const float xb = pb[b*4+0], yb = pb[b*4+1], wb = pb[b*4+2], hb = pb[b*4+3];
    const float xm = pm[b*4+0], ym = pm[b*4+1], wm = pm[b*4+2], hm = pm[b*4+3];
    const bool flb = (fb[b] != 0), flm = (fm[b] != 0);
    float accb[4]={0,0,0,0}, accm[4]={0,0,0,0}, accd[4]={0,0,0,0};
    if (tid < 5 * NPIX) {
        const int q = tid % NPIX, gl = tid / NPIX;
        const float4* bp = base4   + (size_t)b * NG4 + q;
        const float4* mp = moment4 + (size_t)b * NG4 + q;
        for (int g = gl; g < NGRP; g += 5) {
            const float4 x = bp[(size_t)g * NPIX];
            const float4 y = mp[(size_t)g * NPIX];
            accb[0]=fmaf(x.x,x.x,accb[0]); accm[0]=fmaf(y.x,y.x,accm[0]); accd[0]=fmaf(x.x,y.x,accd[0]);
            accb[1]=fmaf(x.y,x.y,accb[1]); accm[1]=fmaf(y.y,y.y,accm[1]); accd[1]=fmaf(x.y,y.y,accd[1]);
            accb[2]=fmaf(x.z,x.z,accb[2]); accm[2]=fmaf(y.z,y.z,accm[2]); accd[2]=fmaf(x.z,y.z,accd[2]);
            accb[3]=fmaf(x.w,x.w,accb[3]); accm[3]=fmaf(y.w,y.w,accm[3]); accd[3]=fmaf(x.w,y.w,accd[3]);
        }
    }
    __syncthreads();
    if (tid < 5 * NPIX) {
        const int q = tid % NPIX;
        #pragma unroll
        for (int e = 0; e < 4; ++e) {
            const int j = (4 * q + e) % NPIX;
            atomicAdd(&lds_sqb[j], accb[e]);
            atomicAdd(&lds_sqm[j], accm[e]);
            atomicAdd(&lds_dot[j], accd[e]);
        }
    }
    __syncthreads();
    if (tid < NPIX) {
        float nb = fmaxf(sqrtf(lds_sqb[tid]), EPSN);
        float nm = fmaxf(sqrtf(lds_sqm[tid]), EPSN);
        cosj[tid] = lds_dot[tid] / (nb * nm);
        const int i = tid / SDIM, jj = tid % SDIM;
        const float ti = (float)i * (1.0f/6.0f);
        const int jb = flb ? (6-jj) : jj, jm = flm ? (6-jj) : jj;
        gbx[tid] = xb + wb * ti;
        gby[tid] = yb + hb * ((float)jb * (1.0f/6.0f));
        gmx[tid] = xm + wm * ti;
        gmy[tid] = ym + hm * ((float)jm * (1.0f/6.0f));
    }
    __syncthreads();
    const float thrb2 = THRESH*THRESH*(wb*wb+hb*hb);
    const float thrm2 = THRESH*THRESH*(wm*wm+hm*hm);
    float sb = 0.f, sm = 0.f; int nnzb = 0, nnzm = 0;
    for (int p = tid; p < NPIX*NPIX; p += 256) {
        const int i = p / NPIX, j = p - i*NPIX;
        const float dx = gbx[i]-gmx[j], dy = gby[i]-gmy[j];
        const float d2 = dx*dx + dy*dy;
        if (d2 < thrb2) { ++nnzb; sb += cosj[j]; }
        if (d2 < thrm2) { ++nnzm; sm += cosj[i]; }
    }
    for (int off = 32; off; off >>= 1) {
        sb += __shfl_down(sb,off); sm += __shfl_down(sm,off);
        nnzb += __shfl_down(nnzb,off); nnzm += __shfl_down(nnzm,off);
    }
    const int wid = tid >> 6;
    if ((tid & 63) == 0) {
        red[wid*4+0]=sb; red[wid*4+1]=sm; red[wid*4+2]=(float)nnzb; red[wid*4+3]=(float)nnzm;
    }
    __syncthreads();
    if (tid == 0) {
        float SB=0,SM=0,NB=0,NM=0;
        for (int w=0;w<4;++w){SB+=red[w*4+0];SM+=red[w*4+1];NB+=red[w*4+2];NM+=red[w*4+3];}
        const float lossb = (NB>0.f)?SB/NB:0.f, lossm = (NM>0.f)?SM/NM:0.f;
        const float cx1=xb+0.5f*wb, cx2=xm+0.5f*wm, cy1=yb+0.5f*hb, cy2=ym+0.5f*hm;
        const bool inter = (fabsf(cx1-cx2)*2.f < wb+wm) && (fabsf(cy1-cy2)*2.f < hb+hm);
        if (inter) { atomicAdd(&accum[0], -(lossb+lossm)); atomicAdd(&accum[1], 1.f); }
    }
}

__global__ void pixpro_mono_final(const float* __restrict__ accum,
                                  float* __restrict__ out)
{
    out[0] = accum[0] / fmaxf(accum[1], 1.0f);
}

// ============================= launch ======================================
extern "C" void kernel_launch(void* const* d_in, const int* in_sizes, int n_in,
                              void* d_out, int out_size, void* d_ws, size_t ws_size,
                              hipStream_t stream)
{
    const float4* base4   = (const float4*)d_in[0];
    const float4* moment4 = (const float4*)d_in[1];
    const float*  pbase   = (const float*)d_in[2];
    const float*  pmom    = (const float*)d_in[3];
    const int*    fbase   = (const int*)d_in[4];
    const int*    fmom    = (const int*)d_in[5];
    float* out = (float*)d_out;

    const int B = in_sizes[2] / 4;  // p_base is (B,4)

    const size_t need = (size_t)B * CHUNKS * (3 * NPIX) * sizeof(float)
                      + (size_t)B * 2 * sizeof(float);
    if (ws_size >= need) {
        float* partial = (float*)d_ws;
        float* perb    = partial + (size_t)B * CHUNKS * (3 * NPIX);
        pixpro_reduce<<<B * CHUNKS, 256, 0, stream>>>(base4, moment4, partial);
        pixpro_pairs<<<B, 64, 0, stream>>>(partial, pbase, pmom, fbase, fmom, perb);
        pixpro_final<<<1, 1024, 0, stream>>>(perb, out, B);
    } else {
        float* accum = (float*)d_ws;  // 2 floats
        hipMemsetAsync(accum, 0, 2 * sizeof(float), stream);
        pixpro_mono<<<B, 256, 0, stream>>>(base4, moment4, pbase, pmom, fbase, fmom, accum);
        pixpro_mono_final<<<1, 1, 0, stream>>>(accum, out);
    }
}

// Round 5
// 71.613 us; speedup vs baseline: 1.0393x; 1.0164x over previous
//
#include <hip/hip_runtime.h>

typedef float f32x4 __attribute__((ext_vector_type(4)));

#define SDIM 7
#define NPIX 49                  // S*S
#define CCH 512
#define FLAT (CCH * NPIX)        // 25088 floats per batch per tensor
#define NG4  (FLAT / 4)          // 6272 float4 per batch per tensor
#define NGRP (CCH / 4)           // 128 4-channel groups
#define CHUNKS 4
#define GPC (NGRP / CHUNKS)      // 32 groups per chunk
#define KITER (GPC / 4)          // 8 groups per gl-lane
#define THRESH 0.7f
#define EPSN 1e-6f

// ============================= Kernel A ====================================
// grid = B*CHUNKS blocks. Block (b,chunk) reduces 128 channels for all 49
// pixels. 196 active threads = 49 q-slots x 4 gl-lanes.
// R3/R4 lesson: source-level staging + sched_barrier is undone by IR-level
// load sinking (VGPR stayed 32-36 => ~2 loads in flight, ~200cyc serialized
// per load). Fix: issue the 16 loads as volatile inline asm (cannot be moved
// or split), one hand-written s_waitcnt vmcnt(0), then sched_barrier(0) so
// no consumer is hoisted above the wait (the compiler does not model vmcnt
// for asm outputs). 16 global_load_dwordx4 in flight per thread by
// construction.
__global__ __launch_bounds__(256) void pixpro_reduce(
    const f32x4* __restrict__ base4, const f32x4* __restrict__ moment4,
    float* __restrict__ partial)
{
    const int bid   = blockIdx.x;
    const int b     = bid >> 2;
    const int chunk = bid & 3;
    const int tid   = threadIdx.x;

    __shared__ float lds[3 * NPIX];
    if (tid < 3 * NPIX) lds[tid] = 0.f;
    __syncthreads();

    if (tid < 4 * NPIX) {
        const int q  = tid % NPIX;       // float4 slot within a 4-ch group
        const int gl = tid / NPIX;       // 0..3
        const f32x4* bp = base4   + (size_t)b * NG4
                        + (size_t)(chunk * GPC + gl) * NPIX + q;
        const f32x4* mp = moment4 + (size_t)b * NG4
                        + (size_t)(chunk * GPC + gl) * NPIX + q;

        f32x4 xs[KITER], ys[KITER];
        #pragma unroll
        for (int k = 0; k < KITER; ++k) {
            asm volatile("global_load_dwordx4 %0, %1, off"
                         : "=v"(xs[k])
                         : "v"(bp + (size_t)(4 * k) * NPIX));
            asm volatile("global_load_dwordx4 %0, %1, off"
                         : "=v"(ys[k])
                         : "v"(mp + (size_t)(4 * k) * NPIX));
        }
        asm volatile("s_waitcnt vmcnt(0)");
        __builtin_amdgcn_sched_barrier(0);   // nothing crosses the wait

        float accb[4] = {0.f, 0.f, 0.f, 0.f};
        float accm[4] = {0.f, 0.f, 0.f, 0.f};
        float accd[4] = {0.f, 0.f, 0.f, 0.f};
        #pragma unroll
        for (int k = 0; k < KITER; ++k) {
            const f32x4 x = xs[k];
            const f32x4 y = ys[k];
            #pragma unroll
            for (int e = 0; e < 4; ++e) {
                accb[e] = fmaf(x[e], x[e], accb[e]);
                accm[e] = fmaf(y[e], y[e], accm[e]);
                accd[e] = fmaf(x[e], y[e], accd[e]);
            }
        }
        #pragma unroll
        for (int e = 0; e < 4; ++e) {
            const int j = (4 * q + e) % NPIX;   // static per (q,e)
            atomicAdd(&lds[j],            accb[e]);
            atomicAdd(&lds[NPIX + j],     accm[e]);
            atomicAdd(&lds[2 * NPIX + j], accd[e]);
        }
    }
    __syncthreads();

    if (tid < 3 * NPIX)
        partial[(size_t)bid * (3 * NPIX) + tid] = lds[tid];
}

// ============================= Kernel B ====================================
// One 64-thread block (single wave) per batch b: merge 4 chunk partials ->
// cos[j]; warp grids; 49x49 pair loop; write (contrib, interFlag) to slot b.
__global__ __launch_bounds__(64) void pixpro_pairs(
    const float* __restrict__ partial,
    const float* __restrict__ pb, const float* __restrict__ pm,
    const int* __restrict__ fb, const int* __restrict__ fm,
    float* __restrict__ perb)
{
    const int b   = blockIdx.x;
    const int tid = threadIdx.x;

    __shared__ float cosj[NPIX];
    __shared__ float gbx[NPIX], gby[NPIX], gmx[NPIX], gmy[NPIX];

    const float xb = pb[b * 4 + 0], yb = pb[b * 4 + 1];
    const float wb = pb[b * 4 + 2], hb = pb[b * 4 + 3];
    const float xm = pm[b * 4 + 0], ym = pm[b * 4 + 1];
    const float wm = pm[b * 4 + 2], hm = pm[b * 4 + 3];
    const bool flb = (fb[b] != 0);
    const bool flm = (fm[b] != 0);

    if (tid < NPIX) {
        float sqb = 0.f, sqm = 0.f, dt = 0.f;
        #pragma unroll
        for (int c = 0; c < CHUNKS; ++c) {
            const float* p = partial + (size_t)(b * CHUNKS + c) * (3 * NPIX);
            sqb += p[tid];
            sqm += p[NPIX + tid];
            dt  += p[2 * NPIX + tid];
        }
        const float nb = fmaxf(sqrtf(sqb), EPSN);
        const float nm = fmaxf(sqrtf(sqm), EPSN);
        cosj[tid] = dt / (nb * nm);

        // grid: n = i*7 + jj ; g[i][jj] = (gx[i], gy[flip ? 6-jj : jj])
        const int i  = tid / SDIM;
        const int jj = tid % SDIM;
        const float ti = (float)i * (1.0f / 6.0f);
        const int jb = flb ? (6 - jj) : jj;
        const int jm = flm ? (6 - jj) : jj;
        gbx[tid] = xb + wb * ti;
        gby[tid] = yb + hb * ((float)jb * (1.0f / 6.0f));
        gmx[tid] = xm + wm * ti;
        gmy[tid] = ym + hm * ((float)jm * (1.0f / 6.0f));
    }
    __syncthreads();

    // A_b[i][j]: dist(gb[i],gm[j]) < 0.7*diag_b -> s_b += cos[j]
    // A_m (after swapaxes): dist(gb[i],gm[j]) < 0.7*diag_m -> s_m += cos[i]
    const float thrb2 = THRESH * THRESH * (wb * wb + hb * hb);
    const float thrm2 = THRESH * THRESH * (wm * wm + hm * hm);
    float sb = 0.f, sm = 0.f;
    int nnzb = 0, nnzm = 0;
    for (int p = tid; p < NPIX * NPIX; p += 64) {
        const int i = p / NPIX;
        const int j = p - i * NPIX;
        const float dx = gbx[i] - gmx[j];
        const float dy = gby[i] - gmy[j];
        const float d2 = dx * dx + dy * dy;
        if (d2 < thrb2) { ++nnzb; sb += cosj[j]; }
        if (d2 < thrm2) { ++nnzm; sm += cosj[i]; }
    }
    #pragma unroll
    for (int off = 32; off; off >>= 1) {
        sb   += __shfl_down(sb, off);
        sm   += __shfl_down(sm, off);
        nnzb += __shfl_down(nnzb, off);
        nnzm += __shfl_down(nnzm, off);
    }
    if (tid == 0) {
        const float lossb = (nnzb > 0) ? sb / (float)nnzb : 0.f;
        const float lossm = (nnzm > 0) ? sm / (float)nnzm : 0.f;
        const float cx1 = xb + 0.5f * wb, cx2 = xm + 0.5f * wm;
        const float cy1 = yb + 0.5f * hb, cy2 = ym + 0.5f * hm;
        const bool inter = (fabsf(cx1 - cx2) * 2.f < wb + wm) &&
                           (fabsf(cy1 - cy2) * 2.f < hb + hm);
        perb[b * 2 + 0] = inter ? -(lossb + lossm) : 0.f;
        perb[b * 2 + 1] = inter ? 1.f : 0.f;
    }
}

// ============================= Kernel C ====================================
__global__ __launch_bounds__(1024) void pixpro_final(
    const float* __restrict__ perb, float* __restrict__ out, int B)
{
    const int tid = threadIdx.x;
    float c = 0.f, n = 0.f;
    for (int i = tid; i < B; i += 1024) {
        c += perb[2 * i + 0];
        n += perb[2 * i + 1];
    }
    #pragma unroll
    for (int off = 32; off; off >>= 1) {
        c += __shfl_down(c, off);
        n += __shfl_down(n, off);
    }
    __shared__ float red[32];
    const int wid = tid >> 6;
    if ((tid & 63) == 0) { red[wid * 2] = c; red[wid * 2 + 1] = n; }
    __syncthreads();
    if (tid == 0) {
        float C = 0.f, N = 0.f;
        for (int w = 0; w < 16; ++w) { C += red[w * 2]; N += red[w * 2 + 1]; }
        out[0] = C / fmaxf(N, 1.0f);
    }
}

// ===================== Fallback mono kernel (small ws) =====================
__global__ __launch_bounds__(256) void pixpro_mono(
    const float4* __restrict__ base4, const float4* __restrict__ moment4,
    const float* __restrict__ pb, const float* __restrict__ pm,
    const int* __restrict__ fb, const int* __restrict__ fm,
    float* __restrict__ accum)
{
    const int b   = blockIdx.x;
    const int tid = threadIdx.x;
    __shared__ float lds_sqb[NPIX], lds_sqm[NPIX], lds_dot[NPIX];
    __shared__ float cosj[NPIX], gbx[NPIX], gby[NPIX], gmx[NPIX], gmy[NPIX];
    __shared__ float red[16];
    if (tid < NPIX) { lds_sqb[tid]=0.f; lds_sqm[tid]=0.f; lds_dot[tid]=0.f; }
    const float xb = pb[b*4+0], yb = pb[b*4+1], wb = pb[b*4+2], hb = pb[b*4+3];
    const float xm = pm[b*4+0], ym = pm[b*4+1], wm = pm[b*4+2], hm = pm[b*4+3];
    const bool flb = (fb[b] != 0), flm = (fm[b] != 0);
    float accb[4]={0,0,0,0}, accm[4]={0,0,0,0}, accd[4]={0,0,0,0};
    if (tid < 5 * NPIX) {
        const int q = tid % NPIX, gl = tid / NPIX;
        const float4* bp = base4   + (size_t)b * NG4 + q;
        const float4* mp = moment4 + (size_t)b * NG4 + q;
        for (int g = gl; g < NGRP; g += 5) {
            const float4 x = bp[(size_t)g * NPIX];
            const float4 y = mp[(size_t)g * NPIX];
            accb[0]=fmaf(x.x,x.x,accb[0]); accm[0]=fmaf(y.x,y.x,accm[0]); accd[0]=fmaf(x.x,y.x,accd[0]);
            accb[1]=fmaf(x.y,x.y,accb[1]); accm[1]=fmaf(y.y,y.y,accm[1]); accd[1]=fmaf(x.y,y.y,accd[1]);
            accb[2]=fmaf(x.z,x.z,accb[2]); accm[2]=fmaf(y.z,y.z,accm[2]); accd[2]=fmaf(x.z,y.z,accd[2]);
            accb[3]=fmaf(x.w,x.w,accb[3]); accm[3]=fmaf(y.w,y.w,accm[3]); accd[3]=fmaf(x.w,y.w,accd[3]);
        }
    }
    __syncthreads();
    if (tid < 5 * NPIX) {
        const int q = tid % NPIX;
        #pragma unroll
        for (int e = 0; e < 4; ++e) {
            const int j = (4 * q + e) % NPIX;
            atomicAdd(&lds_sqb[j], accb[e]);
            atomicAdd(&lds_sqm[j], accm[e]);
            atomicAdd(&lds_dot[j], accd[e]);
        }
    }
    __syncthreads();
    if (tid < NPIX) {
        float nb = fmaxf(sqrtf(lds_sqb[tid]), EPSN);
        float nm = fmaxf(sqrtf(lds_sqm[tid]), EPSN);
        cosj[tid] = lds_dot[tid] / (nb * nm);
        const int i = tid / SDIM, jj = tid % SDIM;
        const float ti = (float)i * (1.0f/6.0f);
        const int jb = flb ? (6-jj) : jj, jm = flm ? (6-jj) : jj;
        gbx[tid] = xb + wb * ti;
        gby[tid] = yb + hb * ((float)jb * (1.0f/6.0f));
        gmx[tid] = xm + wm * ti;
        gmy[tid] = ym + hm * ((float)jm * (1.0f/6.0f));
    }
    __syncthreads();
    const float thrb2 = THRESH*THRESH*(wb*wb+hb*hb);
    const float thrm2 = THRESH*THRESH*(wm*wm+hm*hm);
    float sb = 0.f, sm = 0.f; int nnzb = 0, nnzm = 0;
    for (int p = tid; p < NPIX*NPIX; p += 256) {
        const int i = p / NPIX, j = p - i*NPIX;
        const float dx = gbx[i]-gmx[j], dy = gby[i]-gmy[j];
        const float d2 = dx*dx + dy*dy;
        if (d2 < thrb2) { ++nnzb; sb += cosj[j]; }
        if (d2 < thrm2) { ++nnzm; sm += cosj[i]; }
    }
    for (int off = 32; off; off >>= 1) {
        sb += __shfl_down(sb,off); sm += __shfl_down(sm,off);
        nnzb += __shfl_down(nnzb,off); nnzm += __shfl_down(nnzm,off);
    }
    const int wid = tid >> 6;
    if ((tid & 63) == 0) {
        red[wid*4+0]=sb; red[wid*4+1]=sm; red[wid*4+2]=(float)nnzb; red[wid*4+3]=(float)nnzm;
    }
    __syncthreads();
    if (tid == 0) {
        float SB=0,SM=0,NB=0,NM=0;
        for (int w=0;w<4;++w){SB+=red[w*4+0];SM+=red[w*4+1];NB+=red[w*4+2];NM+=red[w*4+3];}
        const float lossb = (NB>0.f)?SB/NB:0.f, lossm = (NM>0.f)?SM/NM:0.f;
        const float cx1=xb+0.5f*wb, cx2=xm+0.5f*wm, cy1=yb+0.5f*hb, cy2=ym+0.5f*hm;
        const bool inter = (fabsf(cx1-cx2)*2.f < wb+wm) && (fabsf(cy1-cy2)*2.f < hb+hm);
        if (inter) { atomicAdd(&accum[0], -(lossb+lossm)); atomicAdd(&accum[1], 1.f); }
    }
}

__global__ void pixpro_mono_final(const float* __restrict__ accum,
                                  float* __restrict__ out)
{
    out[0] = accum[0] / fmaxf(accum[1], 1.0f);
}

// ============================= launch ======================================
extern "C" void kernel_launch(void* const* d_in, const int* in_sizes, int n_in,
                              void* d_out, int out_size, void* d_ws, size_t ws_size,
                              hipStream_t stream)
{
    const float*  pbase   = (const float*)d_in[2];
    const float*  pmom    = (const float*)d_in[3];
    const int*    fbase   = (const int*)d_in[4];
    const int*    fmom    = (const int*)d_in[5];
    float* out = (float*)d_out;

    const int B = in_sizes[2] / 4;  // p_base is (B,4)

    const size_t need = (size_t)B * CHUNKS * (3 * NPIX) * sizeof(float)
                      + (size_t)B * 2 * sizeof(float);
    if (ws_size >= need) {
        const f32x4* base4   = (const f32x4*)d_in[0];
        const f32x4* moment4 = (const f32x4*)d_in[1];
        float* partial = (float*)d_ws;
        float* perb    = partial + (size_t)B * CHUNKS * (3 * NPIX);
        pixpro_reduce<<<B * CHUNKS, 256, 0, stream>>>(base4, moment4, partial);
        pixpro_pairs<<<B, 64, 0, stream>>>(partial, pbase, pmom, fbase, fmom, perb);
        pixpro_final<<<1, 1024, 0, stream>>>(perb, out, B);
    } else {
        const float4* base4   = (const float4*)d_in[0];
        const float4* moment4 = (const float4*)d_in[1];
        float* accum = (float*)d_ws;  // 2 floats
        hipMemsetAsync(accum, 0, 2 * sizeof(float), stream);
        pixpro_mono<<<B, 256, 0, stream>>>(base4, moment4, pbase, pmom, fbase, fmom, accum);
        pixpro_mono_final<<<1, 1, 0, stream>>>(accum, out);
    }
}